// Round 7
// baseline (334.407 us; speedup 1.0000x reference)
//
#include <hip/hip_runtime.h>

// DigiCaps dynamic routing — MFMA recompute, 4-i packed loads + B-masking.
// inputs [512,1152,8] f32, W [10,1152,16,8] f32, out v [512,10,16] f32.
// u_hat[b,j,i,d] = sum_k x[b,i,k] W[j,i,d,k]; logits b_t = u_hat . vsum
// (vsum = running sum of v's) so u_hat is never materialized.
//
// mfma_f32_16x16x32_bf16, C-layout: lane&15 = b(col), (lane>>4)*4+reg = d(row).
// R6 forensics: compiler serialized the 11 frag loads per i (5900 cy/t =
// 11 x ~540 cy L3 round-trips). R7: A-frags pack 4 i's in the K dim (lane
// (kg,bl) holds W[j,i+kg,d=bl,:], 1KB coalesced/instr); per-i u_hat is
// extracted by masking B (4 cndmask/q): mfma(afull, (kg==q)?x:0) zeroes the
// other K-blocks. 11 loads per FOUR i's + sched_barrier(0) -> one batched
// vmcnt stall per group. Grid (32,36) doubles resident waves.

#define NB 512
#define NI 1152
#define NJ 10
#define ND 16

typedef short  bf16x8 __attribute__((ext_vector_type(8)));
typedef float  f32x4  __attribute__((ext_vector_type(4)));

constexpr int   NBG  = 32;   // b-groups of 16
constexpr int   NIGB = 36;   // i-group blocks (32 i each; 8 per wave)
constexpr int   NPT  = 36;   // partials per b
constexpr float EPS_ = 1e-7f;

constexpr size_t XB_ELEMS = (size_t)NB * NI * 8;       // bf16
constexpr size_t WB_ELEMS = (size_t)NJ * NI * ND * 8;  // bf16
constexpr int    XQ = 1179648;                         // x float4 quads
constexpr int    WQ = 368640;                          // W float4 quads

__device__ inline unsigned short f2bf(float f) {  // RNE f32 -> bf16
    unsigned u = __float_as_uint(f);
    return (unsigned short)((u + 0x7fffu + ((u >> 16) & 1u)) >> 16);
}

__global__ __launch_bounds__(256)
void conv_bf16(const float* __restrict__ x, const float* __restrict__ Wg,
               unsigned short* __restrict__ xb, unsigned short* __restrict__ wb)
{
    int t = blockIdx.x * 256 + threadIdx.x;
    if (t < XQ) {
        float4 v = ((const float4*)x)[t];
        ushort4 o;
        o.x = f2bf(v.x); o.y = f2bf(v.y); o.z = f2bf(v.z); o.w = f2bf(v.w);
        ((ushort4*)xb)[t] = o;
    } else if (t - XQ < WQ) {
        int u = t - XQ;
        float4 v = ((const float4*)Wg)[u];
        ushort4 o;
        o.x = f2bf(v.x); o.y = f2bf(v.y); o.z = f2bf(v.z); o.w = f2bf(v.w);
        ((ushort4*)wb)[u] = o;
    }
}

template <int MODE>
__global__ __launch_bounds__(256, 2)
void caps_pass(const unsigned short* __restrict__ xb,
               const unsigned short* __restrict__ wb,
               const float* __restrict__ vsum_g,
               float* __restrict__ part)
{
    __shared__ float s_red[16 * 160];

    const int tid = threadIdx.x, lane = tid & 63, w = tid >> 6;
    const int bl = lane & 15, kg = lane >> 4;
    const int bg = blockIdx.x, ig = blockIdx.y;
    const int b  = bg * 16 + bl;
    const int i0 = ig * 32 + w * 8;      // this wave's 8-i slice

    for (int k = tid; k < 2560; k += 256) s_red[k] = 0.f;

    const f32x4  zero  = {0.f, 0.f, 0.f, 0.f};
    const bf16x8 zerob = {0, 0, 0, 0, 0, 0, 0, 0};
    f32x4 sacc[NJ];
#pragma unroll
    for (int j = 0; j < NJ; ++j) sacc[j] = zero;

    f32x4 vs[NJ];
    if (MODE == 1) {
#pragma unroll
        for (int j = 0; j < NJ; ++j)
            vs[j] = *(const f32x4*)(vsum_g + (size_t)b * 160 + j * 16 + kg * 4);
    }

#pragma unroll
    for (int t4 = 0; t4 < 2; ++t4) {
        const int ii = i0 + t4 * 4 + kg;            // lane's i within the 4-pack
        // A: W[j, ii, d=bl, 0:8] — 64 lanes = 1KB contiguous per j.
        // B: x[b, ii, 0:8]       — 64 distinct 16B rows.
        const unsigned short* wr = wb + (size_t)ii * 128 + bl * 8;
        bf16x8 afull[NJ];
#pragma unroll
        for (int j = 0; j < NJ; ++j)
            afull[j] = *(const bf16x8*)(wr + (size_t)j * NI * 128);
        bf16x8 bfull = *(const bf16x8*)(xb + ((size_t)b * NI + ii) * 8);
        __builtin_amdgcn_sched_barrier(0);   // loads issue together; one vmcnt wait

        if (MODE == 0) {
            // uniform-c: K=32 sums all 4 i's directly.
#pragma unroll
            for (int j = 0; j < NJ; ++j)
                sacc[j] = __builtin_amdgcn_mfma_f32_16x16x32_bf16(afull[j], bfull, sacc[j], 0, 0, 0);
        } else {
#pragma unroll
            for (int q = 0; q < 4; ++q) {
                const bf16x8 bq = (kg == q) ? bfull : zerob;   // isolate K-block q = i0+t4*4+q
                f32x4 uh[NJ];
#pragma unroll
                for (int j = 0; j < NJ; ++j)
                    uh[j] = __builtin_amdgcn_mfma_f32_16x16x32_bf16(afull[j], bq, uh[j] = zero, 0, 0, 0);

                float bd[NJ];
#pragma unroll
                for (int j = 0; j < NJ; ++j) {
                    float v = uh[j][0] * vs[j][0] + uh[j][1] * vs[j][1]
                            + uh[j][2] * vs[j][2] + uh[j][3] * vs[j][3];
                    v += __shfl_xor(v, 16, 64);   // reduce the 4 d-quads
                    v += __shfl_xor(v, 32, 64);
                    bd[j] = v;
                }
                float m = bd[0];
#pragma unroll
                for (int j = 1; j < NJ; ++j) m = fmaxf(m, bd[j]);
                float Z = 0.f;
#pragma unroll
                for (int j = 0; j < NJ; ++j) { bd[j] = __expf(bd[j] - m); Z += bd[j]; }
                const float rZ = 1.f / Z;
#pragma unroll
                for (int j = 0; j < NJ; ++j) {
                    const float c = bd[j] * rZ;
                    sacc[j] += c * uh[j];
                }
            }
        }
    }

    // ---- cross-wave reduce (4 waves, same b-tile, different i-slices)
    __syncthreads();
    const int base = bl * 160 + kg * 4;
#pragma unroll
    for (int j = 0; j < NJ; ++j)
#pragma unroll
        for (int r = 0; r < 4; ++r)
            atomicAdd(&s_red[base + j * 16 + r], sacc[j][r]);
    __syncthreads();

    float* pp = part + ((size_t)ig * NB + bg * 16) * 160;
    for (int k = tid; k < 2560; k += 256) pp[k] = s_red[k];
}

// Sum NPT i-group partials, scale, squash over d (16-lane shfl), update vsum/out.
__global__ __launch_bounds__(256)
void squash_reduce(const float* __restrict__ part, float* __restrict__ vsum_g,
                   float* __restrict__ out, float alpha, int mode)
{
    const int t = blockIdx.x * 256 + threadIdx.x;   // < 81920 = b*160 + j*16 + d
    const float* p = part + t;
    float a0 = 0.f, a1 = 0.f, a2 = 0.f, a3 = 0.f;
#pragma unroll
    for (int ig = 0; ig < NPT; ig += 4) {
        a0 += p[(size_t)ig * 81920];
        a1 += p[(size_t)(ig + 1) * 81920];
        a2 += p[(size_t)(ig + 2) * 81920];
        a3 += p[(size_t)(ig + 3) * 81920];
    }
    const float s = ((a0 + a1) + (a2 + a3)) * alpha;

    float sq = s * s;
    sq += __shfl_xor(sq, 1, 64);
    sq += __shfl_xor(sq, 2, 64);
    sq += __shfl_xor(sq, 4, 64);
    sq += __shfl_xor(sq, 8, 64);
    const float sc = sq / ((1.f + sq) * sqrtf(sq + EPS_));
    const float v  = sc * s;

    if (mode == 0)      vsum_g[t] = v;
    else if (mode == 1) vsum_g[t] += v;
    else                out[t] = v;
}

extern "C" void kernel_launch(void* const* d_in, const int* in_sizes, int n_in,
                              void* d_out, int out_size, void* d_ws, size_t ws_size,
                              hipStream_t stream)
{
    const float* inp = (const float*)d_in[0];
    const float* Wg  = (const float*)d_in[1];
    float* out = (float*)d_out;

    unsigned short* xbp = (unsigned short*)d_ws;
    unsigned short* wbp = xbp + XB_ELEMS;
    float* part = (float*)((char*)d_ws + (XB_ELEMS + WB_ELEMS) * 2);
    float* vsum = part + (size_t)NPT * NB * 160;

    conv_bf16<<<(XQ + WQ + 255) / 256, 256, 0, stream>>>(inp, Wg, xbp, wbp);

    dim3 grid(NBG, NIGB);   // (32,36) = 1152 blocks
    // iter 0: c uniform 1/10 (folded into alpha)
    caps_pass<0><<<grid, 256, 0, stream>>>(xbp, wbp, nullptr, part);
    squash_reduce<<<320, 256, 0, stream>>>(part, vsum, out, 0.1f, 0);
    // iter 1: logits = u_hat . v0
    caps_pass<1><<<grid, 256, 0, stream>>>(xbp, wbp, vsum, part);
    squash_reduce<<<320, 256, 0, stream>>>(part, vsum, out, 1.0f, 1);
    // iter 2: logits = u_hat . (v0+v1)
    caps_pass<1><<<grid, 256, 0, stream>>>(xbp, wbp, vsum, part);
    squash_reduce<<<320, 256, 0, stream>>>(part, vsum, out, 1.0f, 2);
}